// Round 5
// baseline (5035.420 us; speedup 1.0000x reference)
//
#include <hip/hip_runtime.h>
#include <stdint.h>

#define VOCAB 32000
#define EMBD 512
#define HID 512
#define BATCH 32
#define SEQL 512

typedef short bf16x8 __attribute__((ext_vector_type(8)));
typedef short bf16x4 __attribute__((ext_vector_type(4)));
typedef float f32x4 __attribute__((ext_vector_type(4)));
typedef unsigned u32x4v __attribute__((ext_vector_type(4)));

static __device__ __forceinline__ float bf2f(short u) {
  union { unsigned u; float f; } c;
  c.u = ((unsigned)(unsigned short)u) << 16;
  return c.f;
}
static __device__ __forceinline__ unsigned short f2bf(float f) {
  union { float f; unsigned u; } c;
  c.f = f;
  unsigned x = c.u;
  unsigned r = (x + 0x7fffu + ((x >> 16) & 1u)) >> 16;
  return (unsigned short)r;
}
static __device__ __forceinline__ unsigned umin2(unsigned a, unsigned b) {
  return a < b ? a : b;
}

// ---------------- f32 -> bf16 convert (8 elems/thread) ----------------
__global__ __launch_bounds__(256) void cvt_f32_bf16(
    const float* __restrict__ src, unsigned short* __restrict__ dst, int n8) {
  int i = blockIdx.x * 256 + threadIdx.x;
  if (i >= n8) return;
  const float4* s = (const float4*)src + (size_t)i * 2;
  float4 a = s[0], b = s[1];
  uint4 p;
  p.x = (unsigned)f2bf(a.x) | ((unsigned)f2bf(a.y) << 16);
  p.y = (unsigned)f2bf(a.z) | ((unsigned)f2bf(a.w) << 16);
  p.z = (unsigned)f2bf(b.x) | ((unsigned)f2bf(b.y) << 16);
  p.w = (unsigned)f2bf(b.z) | ((unsigned)f2bf(b.w) << 16);
  ((uint4*)dst)[i] = p;
}

// ---------------- gx GEMM: gx[s][d][g][b] = x[b,s,:]·W_ih[d,g,:] + b_ih ----
#define GBM 128
#define GBN 128
#define GBK 64

__global__ __launch_bounds__(256) void gemm_gx(
    const int* __restrict__ enc,                 // [B][S]
    const unsigned short* __restrict__ embb,     // [VOCAB][512] bf16
    const unsigned short* __restrict__ wih,      // [3072][512] bf16
    const float* __restrict__ b_ih,              // [3072]
    unsigned short* __restrict__ gx)             // [S][2][1536][32] bf16
{
  __shared__ __align__(16) unsigned short As[GBM * GBK];
  __shared__ __align__(16) unsigned short Bs[GBN * GBK];
  __shared__ int tokl[GBM];

  const int n0 = blockIdx.x * GBN;
  const int m0 = blockIdx.y * GBM;
  const int tid = threadIdx.x;
  if (tid < GBM) {
    int m = m0 + tid;
    tokl[tid] = enc[(m & 31) * SEQL + (m >> 5)];
  }
  __syncthreads();

  const int l = tid & 63, w = tid >> 6;
  const int wr = w >> 1, wc = w & 1;

  f32x4 acc[4][4];
  f32x4 zero = {0.f, 0.f, 0.f, 0.f};
#pragma unroll
  for (int mt = 0; mt < 4; ++mt)
#pragma unroll
    for (int nt = 0; nt < 4; ++nt) acc[mt][nt] = zero;

  for (int kt = 0; kt < 512; kt += GBK) {
#pragma unroll
    for (int it = 0; it < 4; ++it) {  // A stage
      int c = it * 256 + tid;
      int r = c >> 3, kc = c & 7;
      uint4 v = *(const uint4*)(embb + (size_t)tokl[r] * 512 + kt + kc * 8);
      unsigned off = (unsigned)(r * 128 + kc * 16); off ^= (r & 7) << 4;
      *(uint4*)((char*)As + off) = v;
    }
#pragma unroll
    for (int it = 0; it < 4; ++it) {  // B stage
      int c = it * 256 + tid;
      int r = c >> 3, kc = c & 7;
      uint4 v = *(const uint4*)(wih + (size_t)(n0 + r) * 512 + kt + kc * 8);
      unsigned off = (unsigned)(r * 128 + kc * 16); off ^= (r & 7) << 4;
      *(uint4*)((char*)Bs + off) = v;
    }
    __syncthreads();
#pragma unroll
    for (int ks = 0; ks < 2; ++ks) {
      bf16x8 af[4], bfr[4];
#pragma unroll
      for (int mt = 0; mt < 4; ++mt) {
        int r = wr * 64 + mt * 16 + (l & 15);
        unsigned off = (unsigned)(r * 128 + ks * 64 + (l >> 4) * 16);
        off ^= (r & 7) << 4;
        af[mt] = *(const bf16x8*)((char*)As + off);
      }
#pragma unroll
      for (int nt = 0; nt < 4; ++nt) {
        int r = wc * 64 + nt * 16 + (l & 15);
        unsigned off = (unsigned)(r * 128 + ks * 64 + (l >> 4) * 16);
        off ^= (r & 7) << 4;
        bfr[nt] = *(const bf16x8*)((char*)Bs + off);
      }
#pragma unroll
      for (int mt = 0; mt < 4; ++mt)
#pragma unroll
        for (int nt = 0; nt < 4; ++nt)
          acc[mt][nt] = __builtin_amdgcn_mfma_f32_16x16x32_bf16(
              af[mt], bfr[nt], acc[mt][nt], 0, 0, 0);
    }
    __syncthreads();
  }

#pragma unroll
  for (int nt = 0; nt < 4; ++nt) {
    int n = n0 + wc * 64 + nt * 16 + (l & 15);
    int d = n >= 1536 ? 1 : 0;
    int g = n - d * 1536;
    float bias = b_ih[n];
#pragma unroll
    for (int mt = 0; mt < 4; ++mt) {
      int mbase = m0 + wr * 64 + mt * 16 + (l >> 4) * 4;
      int s = mbase >> 5;
      int b = mbase & 31;
      unsigned v0 = (unsigned)f2bf(acc[mt][nt][0] + bias) |
                    ((unsigned)f2bf(acc[mt][nt][1] + bias) << 16);
      unsigned v1 = (unsigned)f2bf(acc[mt][nt][2] + bias) |
                    ((unsigned)f2bf(acc[mt][nt][3] + bias) << 16);
      size_t off = ((size_t)(s * 2 + d) * 1536 + g) * 32 + b;
      uint2 pv; pv.x = v0; pv.y = v1;
      *(uint2*)(gx + off) = pv;
    }
  }
}

// ---------------- persistent GRU scan: XCD-L2 transport + flag polling -----
// 256 WGs; bid%8==0 -> dir0 (XCD0), ==1 -> dir1 (XCD1), rest exit. Per-WAVE
// protocol (no in-loop __syncthreads): store tagged h (plain->own L2 + sc1->
// MALL mirror) -> vmcnt(0) -> per-wave flag (plain + sc1) -> out/gx (off
// critical path). Consumers poll 64 flags (1 sc0 dword/lane), then load h
// once (sc0 dwordx4) and validate per-word tags; timeout/invalid => sticky
// per-wave fallback to the MALL path (R3-proven). Correct for any placement.
#define JW 16

__global__ __launch_bounds__(128) void scan_gru(
    const unsigned short* __restrict__ gx,    // [S][2][1536][32]
    const unsigned short* __restrict__ whh,   // [2][1536][512] bf16
    const float* __restrict__ bhh,            // [2][1536]
    unsigned* __restrict__ hbL2,              // [2][2][32][512] u32 tagged
    unsigned* __restrict__ hbMall,            // [2][2][32][512] u32 tagged
    unsigned* __restrict__ flagsF,            // [2][256] u32 (64 used/dir)
    unsigned* __restrict__ flagsM,            // [2][256] u32 (64 used/dir)
    float* __restrict__ out)                  // encoded + hidden
{
  const int bid = blockIdx.x;
  const int r8 = bid & 7;
  if (r8 > 1) return;                 // 192 of 256 WGs exit immediately
  const int d = r8;
  const int wg = bid >> 3;            // 0..31

  __shared__ __align__(16) unsigned short Wl[48 * 512];  // 48KB, swizzled

  const int j0 = wg * JW;
  const int tid = threadIdx.x;
  const int l = tid & 63;
  const int w = tid >> 6;             // wave = b-half

  // stage W_hh slice: rows lr = gate*16 + jj -> global row gate*512+j0+jj
  for (int it = 0; it < 24; ++it) {
    int c = it * 128 + tid;           // 16B chunks; 64 per row
    int lr = c >> 6, kc = c & 63;
    int gate = lr >> 4, jj = lr & 15;
    uint4 v = *(const uint4*)(whh +
        (size_t)(d * 1536 + gate * 512 + j0 + jj) * 512 + kc * 8);
    unsigned off = (unsigned)(lr * 1024 + kc * 16); off ^= (lr & 7) << 4;
    *(uint4*)((char*)Wl + off) = v;
  }

  const int jl = l & 15;
  const int jglob = j0 + jl;
  const int b0 = w * 16;
  const int brow = b0 + (l >> 4) * 4; // first of 4 C-rows (batch) this lane owns
  const int arow = b0 + (l & 15);     // A-frag row (batch) this lane reads
  const float bh_r = bhh[d * 1536 + jglob];
  const float bh_z = bhh[d * 1536 + 512 + jglob];
  const float bh_n = bhh[d * 1536 + 1024 + jglob];

  const int fidx = wg * 2 + w;        // 64 per-wave flags per dir
  unsigned* myFF = flagsF + d * 256 + fidx;
  unsigned* myFM = flagsM + d * 256 + fidx;
  const unsigned* FFp = flagsF + d * 256 + l;   // lane l polls flag l
  const unsigned* FMp = flagsM + d * 256 + l;

  float hold[4] = {0.f, 0.f, 0.f, 0.f};
  bool fastok = true;

  __syncthreads();  // Wl ready (only barrier in the kernel)

  // prefetch gx for t=0
  bf16x4 gr, gz, gn;
  {
    size_t gb = (size_t)d * 1536 * 32;
    gr = *(const bf16x4*)(gx + gb + (size_t)jglob * 32 + brow);
    gz = *(const bf16x4*)(gx + gb + (size_t)(512 + jglob) * 32 + brow);
    gn = *(const bf16x4*)(gx + gb + (size_t)(1024 + jglob) * 32 + brow);
  }

  for (int t = 0; t < SEQL; ++t) {
    f32x4 accr = {0.f, 0.f, 0.f, 0.f};
    f32x4 accz = accr, accn = accr;

    if (t > 0) {
      u32x4v q[32];
      const unsigned tagv = (unsigned)t;
      const size_t pbase = (size_t)(d * 2 + ((t - 1) & 1)) * 32 * 512;
      bool valid = false;

      if (fastok) {
        // 1) cheap flag poll: one sc0 dword per lane
        bool fok = false;
        const int cap = (t == 1) ? 3000 : 48;
        for (int it = 0; it < cap; ++it) {
          unsigned fv;
          asm volatile("global_load_dword %0, %1, off sc0"
                       : "=v"(fv) : "v"(FFp));
          asm volatile("s_waitcnt vmcnt(0)" ::: "memory");
          if (__ballot(fv >= tagv) == ~0ull) { fok = true; break; }
          __builtin_amdgcn_s_sleep(1);
        }
        // 2) one-shot data load + tag validate (retry few)
        if (fok) {
          const unsigned* lp = hbL2 + pbase + (size_t)arow * 512 + (l >> 4) * 8;
          for (int it = 0; it < 16 && !valid; ++it) {
#pragma unroll
            for (int ks = 0; ks < 16; ++ks) {
              asm volatile("global_load_dwordx4 %0, %1, off offset:%2 sc0"
                           : "=v"(q[2 * ks]) : "v"(lp), "i"(ks * 128));
              asm volatile("global_load_dwordx4 %0, %1, off offset:%2 sc0"
                           : "=v"(q[2 * ks + 1]) : "v"(lp), "i"(ks * 128 + 16));
            }
            asm volatile("s_waitcnt vmcnt(0)" ::: "memory");
            __builtin_amdgcn_sched_barrier(0);
            unsigned mn = 0xffffffffu;
#pragma unroll
            for (int i = 0; i < 32; ++i) {
              unsigned a = umin2(q[i][0], q[i][1]);
              unsigned b2 = umin2(q[i][2], q[i][3]);
              mn = umin2(mn, umin2(a, b2));
            }
            if (__ballot((mn >> 16) == tagv) == ~0ull) valid = true;
            else __builtin_amdgcn_s_sleep(1);
          }
        }
        if (!valid && t >= 2) fastok = false;  // sticky demote: placement bad
      }

      if (!valid) {  // MALL fallback (placement-independent, R3-proven)
        for (;;) {
          unsigned fv = __hip_atomic_load(FMp, __ATOMIC_RELAXED,
                                          __HIP_MEMORY_SCOPE_AGENT);
          if (__ballot(fv >= tagv) == ~0ull) break;
          __builtin_amdgcn_s_sleep(2);
        }
        const unsigned long long* hqb =
            (const unsigned long long*)(hbMall + pbase) +
            (size_t)arow * 256 + (l >> 4) * 4;
        for (;;) {
          unsigned mn = 0xffffffffu;
#pragma unroll
          for (int ks = 0; ks < 16; ++ks) {
            union { unsigned long long d2[2]; u32x4v v; } ua, ub;
            ua.d2[0] = __hip_atomic_load(hqb + ks * 16 + 0,
                __ATOMIC_RELAXED, __HIP_MEMORY_SCOPE_AGENT);
            ua.d2[1] = __hip_atomic_load(hqb + ks * 16 + 1,
                __ATOMIC_RELAXED, __HIP_MEMORY_SCOPE_AGENT);
            ub.d2[0] = __hip_atomic_load(hqb + ks * 16 + 2,
                __ATOMIC_RELAXED, __HIP_MEMORY_SCOPE_AGENT);
            ub.d2[1] = __hip_atomic_load(hqb + ks * 16 + 3,
                __ATOMIC_RELAXED, __HIP_MEMORY_SCOPE_AGENT);
            q[2 * ks] = ua.v;
            q[2 * ks + 1] = ub.v;
            unsigned a = umin2(umin2(ua.v[0], ua.v[1]), umin2(ua.v[2], ua.v[3]));
            unsigned b2 = umin2(umin2(ub.v[0], ub.v[1]), umin2(ub.v[2], ub.v[3]));
            mn = umin2(mn, umin2(a, b2));
          }
          if (__ballot((mn >> 16) == tagv) == ~0ull) break;
          __builtin_amdgcn_s_sleep(2);
        }
      }

      // fused repack (strip tags -> bf16x8 A-frags) + MFMA
#pragma unroll
      for (int ks = 0; ks < 16; ++ks) {
        union { unsigned u[4]; bf16x8 v; } af;
        af.u[0] = __builtin_amdgcn_perm(q[2 * ks][1], q[2 * ks][0], 0x05040100u);
        af.u[1] = __builtin_amdgcn_perm(q[2 * ks][3], q[2 * ks][2], 0x05040100u);
        af.u[2] = __builtin_amdgcn_perm(q[2 * ks + 1][1], q[2 * ks + 1][0], 0x05040100u);
        af.u[3] = __builtin_amdgcn_perm(q[2 * ks + 1][3], q[2 * ks + 1][2], 0x05040100u);
        unsigned kb = (unsigned)(ks * 64 + (l >> 4) * 16);
        unsigned r0 = (unsigned)jl, r1 = (unsigned)(16 + jl), r2 = (unsigned)(32 + jl);
        bf16x8 bR = *(const bf16x8*)((char*)Wl + ((r0 * 1024 + kb) ^ ((r0 & 7) << 4)));
        bf16x8 bZ = *(const bf16x8*)((char*)Wl + ((r1 * 1024 + kb) ^ ((r1 & 7) << 4)));
        bf16x8 bN = *(const bf16x8*)((char*)Wl + ((r2 * 1024 + kb) ^ ((r2 & 7) << 4)));
        accr = __builtin_amdgcn_mfma_f32_16x16x32_bf16(af.v, bR, accr, 0, 0, 0);
        accz = __builtin_amdgcn_mfma_f32_16x16x32_bf16(af.v, bZ, accz, 0, 0, 0);
        accn = __builtin_amdgcn_mfma_f32_16x16x32_bf16(af.v, bN, accn, 0, 0, 0);
      }
    }

    // gates
#pragma unroll
    for (int i = 0; i < 4; ++i) {
      float ghr = accr[i] + bh_r;
      float ghz = accz[i] + bh_z;
      float ghn = accn[i] + bh_n;
      float pr = bf2f(gr[i]) + ghr;
      float pz = bf2f(gz[i]) + ghz;
      float r = 1.f / (1.f + __expf(-pr));
      float z = 1.f / (1.f + __expf(-pz));
      float n = tanhf(bf2f(gn[i]) + r * ghn);
      hold[i] = (1.f - z) * n + z * hold[i];
    }

    if (t < SEQL - 1) {
      // publish tagged h: plain -> own XCD L2, sc1 -> MALL mirror
      const size_t obase = (size_t)(d * 2 + (t & 1)) * 32 * 512;
      unsigned* pl = hbL2 + obase;
      unsigned* pm = hbMall + obase;
      const unsigned tagw = ((unsigned)(t + 1)) << 16;
      const unsigned tagp = (unsigned)(t + 1);
#pragma unroll
      for (int i = 0; i < 4; ++i) {
        unsigned wv = tagw | (unsigned)f2bf(hold[i]);
        size_t hoff = (size_t)(brow + i) * 512 + jglob;
        pl[hoff] = wv;
        __hip_atomic_store(pm + hoff, wv,
                           __ATOMIC_RELAXED, __HIP_MEMORY_SCOPE_AGENT);
      }
      asm volatile("s_waitcnt vmcnt(0)" ::: "memory");  // wave-local drain
      if (l == 0) {
        *(volatile unsigned*)myFF = tagp;               // fast flag (own L2)
        __hip_atomic_store(myFM, tagp,
                           __ATOMIC_RELAXED, __HIP_MEMORY_SCOPE_AGENT);
      }
    }

    // out stores: off the critical path (issued after flag publish)
#pragma unroll
    for (int i = 0; i < 4; ++i)
      out[((size_t)(brow + i) * SEQL + t) * 1024 + d * 512 + jglob] = hold[i];
    if (t == SEQL - 1) {
#pragma unroll
      for (int i = 0; i < 4; ++i)
        out[(size_t)BATCH * SEQL * 1024 +
            (size_t)(d * 32 + brow + i) * 512 + jglob] = hold[i];
    }

    if (t < SEQL - 1) {
      // prefetch next gx (independent of h), overlaps peers' publish latency
      size_t gb = ((size_t)(t + 1) * 2 + d) * 1536 * 32;
      gr = *(const bf16x4*)(gx + gb + (size_t)jglob * 32 + brow);
      gz = *(const bf16x4*)(gx + gb + (size_t)(512 + jglob) * 32 + brow);
      gn = *(const bf16x4*)(gx + gb + (size_t)(1024 + jglob) * 32 + brow);
    }
  }
}

extern "C" void kernel_launch(void* const* d_in, const int* in_sizes, int n_in,
                              void* d_out, int out_size, void* d_ws, size_t ws_size,
                              hipStream_t stream) {
  const int* enc = (const int*)d_in[0];
  const float* emb = (const float*)d_in[1];
  const float* wih = (const float*)d_in[2];
  const float* whh = (const float*)d_in[3];
  const float* bih = (const float*)d_in[4];
  const float* bhh = (const float*)d_in[5];
  float* out = (float*)d_out;

  char* ws = (char*)d_ws;
  // layout (16B aligned):
  //   [0, 2048)            flagsF [2][256] u32 (dir stride 1024B)
  //   [4096, 6144)         flagsM [2][256] u32
  //   [8192, 270336)       hbL2   tagged h (plain/L2 path)
  //   [270336, 532480)     hbMall tagged h (sc1/MALL path)
  //   +532480  whh_b 3145728, wih_b 3145728, emb_b 32768000, gx 100663296
  unsigned* flagsF = (unsigned*)ws;
  unsigned* flagsM = (unsigned*)(ws + 4096);
  unsigned* hbL2 = (unsigned*)(ws + 8192);
  unsigned* hbMall = (unsigned*)(ws + 8192 + 262144);
  unsigned short* whh_b = (unsigned short*)(ws + 532480);
  unsigned short* wih_b = (unsigned short*)(ws + 532480 + 3145728);
  unsigned short* emb_b = (unsigned short*)(ws + 532480 + 2 * 3145728);
  unsigned short* gx = (unsigned short*)(ws + 532480 + 2 * 3145728 + 32768000);

  hipMemsetAsync(ws, 0, 532480, stream);  // clear flags + both h buffers
  cvt_f32_bf16<<<768, 256, 0, stream>>>(whh, whh_b, 196608);
  cvt_f32_bf16<<<768, 256, 0, stream>>>(wih, wih_b, 196608);
  cvt_f32_bf16<<<8000, 256, 0, stream>>>(emb, emb_b, 2048000);
  gemm_gx<<<dim3(24, 128), 256, 0, stream>>>(enc, emb_b, wih_b, bih, gx);
  scan_gru<<<256, 128, 0, stream>>>(gx, whh_b, bhh, hbL2, hbMall,
                                    flagsF, flagsM, out);
}

// Round 7
// 3085.088 us; speedup vs baseline: 1.6322x; 1.6322x over previous
//
#include <hip/hip_runtime.h>
#include <stdint.h>

#define VOCAB 32000
#define EMBD 512
#define HID 512
#define BATCH 32
#define SEQL 512

typedef short bf16x8 __attribute__((ext_vector_type(8)));
typedef short bf16x4 __attribute__((ext_vector_type(4)));
typedef float f32x4 __attribute__((ext_vector_type(4)));

#define AGENT __HIP_MEMORY_SCOPE_AGENT
#define RLX __ATOMIC_RELAXED

static __device__ __forceinline__ float bf2f(short u) {
  union { unsigned u; float f; } c;
  c.u = ((unsigned)(unsigned short)u) << 16;
  return c.f;
}
static __device__ __forceinline__ unsigned short f2bf(float f) {
  union { float f; unsigned u; } c;
  c.f = f;
  unsigned x = c.u;
  unsigned r = (x + 0x7fffu + ((x >> 16) & 1u)) >> 16;
  return (unsigned short)r;
}

// ---------------- f32 -> bf16 convert (8 elems/thread) ----------------
__global__ __launch_bounds__(256) void cvt_f32_bf16(
    const float* __restrict__ src, unsigned short* __restrict__ dst, int n8) {
  int i = blockIdx.x * 256 + threadIdx.x;
  if (i >= n8) return;
  const float4* s = (const float4*)src + (size_t)i * 2;
  float4 a = s[0], b = s[1];
  uint4 p;
  p.x = (unsigned)f2bf(a.x) | ((unsigned)f2bf(a.y) << 16);
  p.y = (unsigned)f2bf(a.z) | ((unsigned)f2bf(a.w) << 16);
  p.z = (unsigned)f2bf(b.x) | ((unsigned)f2bf(b.y) << 16);
  p.w = (unsigned)f2bf(b.z) | ((unsigned)f2bf(b.w) << 16);
  ((uint4*)dst)[i] = p;
}

// ---------------- gx GEMM: gx[s][d][g][b] = x[b,s,:]·W_ih[d,g,:] + b_ih ----
#define GBM 128
#define GBN 128
#define GBK 64

__global__ __launch_bounds__(256) void gemm_gx(
    const int* __restrict__ enc,                 // [B][S]
    const unsigned short* __restrict__ embb,     // [VOCAB][512] bf16
    const unsigned short* __restrict__ wih,      // [3072][512] bf16
    const float* __restrict__ b_ih,              // [3072]
    unsigned short* __restrict__ gx)             // [S][2][1536][32] bf16
{
  __shared__ __align__(16) unsigned short As[GBM * GBK];
  __shared__ __align__(16) unsigned short Bs[GBN * GBK];
  __shared__ int tokl[GBM];

  const int n0 = blockIdx.x * GBN;
  const int m0 = blockIdx.y * GBM;
  const int tid = threadIdx.x;
  if (tid < GBM) {
    int m = m0 + tid;
    tokl[tid] = enc[(m & 31) * SEQL + (m >> 5)];
  }
  __syncthreads();

  const int l = tid & 63, w = tid >> 6;
  const int wr = w >> 1, wc = w & 1;

  f32x4 acc[4][4];
  f32x4 zero = {0.f, 0.f, 0.f, 0.f};
#pragma unroll
  for (int mt = 0; mt < 4; ++mt)
#pragma unroll
    for (int nt = 0; nt < 4; ++nt) acc[mt][nt] = zero;

  for (int kt = 0; kt < 512; kt += GBK) {
#pragma unroll
    for (int it = 0; it < 4; ++it) {  // A stage
      int c = it * 256 + tid;
      int r = c >> 3, kc = c & 7;
      uint4 v = *(const uint4*)(embb + (size_t)tokl[r] * 512 + kt + kc * 8);
      unsigned off = (unsigned)(r * 128 + kc * 16); off ^= (r & 7) << 4;
      *(uint4*)((char*)As + off) = v;
    }
#pragma unroll
    for (int it = 0; it < 4; ++it) {  // B stage
      int c = it * 256 + tid;
      int r = c >> 3, kc = c & 7;
      uint4 v = *(const uint4*)(wih + (size_t)(n0 + r) * 512 + kt + kc * 8);
      unsigned off = (unsigned)(r * 128 + kc * 16); off ^= (r & 7) << 4;
      *(uint4*)((char*)Bs + off) = v;
    }
    __syncthreads();
#pragma unroll
    for (int ks = 0; ks < 2; ++ks) {
      bf16x8 af[4], bfr[4];
#pragma unroll
      for (int mt = 0; mt < 4; ++mt) {
        int r = wr * 64 + mt * 16 + (l & 15);
        unsigned off = (unsigned)(r * 128 + ks * 64 + (l >> 4) * 16);
        off ^= (r & 7) << 4;
        af[mt] = *(const bf16x8*)((char*)As + off);
      }
#pragma unroll
      for (int nt = 0; nt < 4; ++nt) {
        int r = wc * 64 + nt * 16 + (l & 15);
        unsigned off = (unsigned)(r * 128 + ks * 64 + (l >> 4) * 16);
        off ^= (r & 7) << 4;
        bfr[nt] = *(const bf16x8*)((char*)Bs + off);
      }
#pragma unroll
      for (int mt = 0; mt < 4; ++mt)
#pragma unroll
        for (int nt = 0; nt < 4; ++nt)
          acc[mt][nt] = __builtin_amdgcn_mfma_f32_16x16x32_bf16(
              af[mt], bfr[nt], acc[mt][nt], 0, 0, 0);
    }
    __syncthreads();
  }

#pragma unroll
  for (int nt = 0; nt < 4; ++nt) {
    int n = n0 + wc * 64 + nt * 16 + (l & 15);
    int d = n >= 1536 ? 1 : 0;
    int g = n - d * 1536;
    float bias = b_ih[n];
#pragma unroll
    for (int mt = 0; mt < 4; ++mt) {
      int mbase = m0 + wr * 64 + mt * 16 + (l >> 4) * 4;
      int s = mbase >> 5;
      int b = mbase & 31;
      unsigned v0 = (unsigned)f2bf(acc[mt][nt][0] + bias) |
                    ((unsigned)f2bf(acc[mt][nt][1] + bias) << 16);
      unsigned v1 = (unsigned)f2bf(acc[mt][nt][2] + bias) |
                    ((unsigned)f2bf(acc[mt][nt][3] + bias) << 16);
      size_t off = ((size_t)(s * 2 + d) * 1536 + g) * 32 + b;
      uint2 pv; pv.x = v0; pv.y = v1;
      *(uint2*)(gx + off) = pv;
    }
  }
}

// ---------------- persistent GRU scan, canary-gated tagged dataflow --------
// 64 WGs = 2 dirs x 32 j-slices (JW=16), 128 thr = 2 waves (b-halves).
// All cross-WG traffic via relaxed AGENT-scope (sc1) atomics — the only
// transport proven reliable on this chip (R2/R3). h words are u32
// {tag:16 | h_bf16:16}. Consumers first poll a 4B CANARY per producer
// (lane l polls producer l&31's word for its own row), then do ONE bulk
// read validated by min-tree over tags; retry only on the rare store-order
// window. Exact-match tags + 2-deep ping-pong make lapping impossible
// (producer can't overwrite parity p until every consumer finished reading
// it — same proof as R3, which passed all replays). No fences, no flags,
// no __syncthreads in the loop.
#define JW 16

__global__ __launch_bounds__(128) void scan_gru(
    const unsigned short* __restrict__ gx,    // [S][2][1536][32]
    const unsigned short* __restrict__ whh,   // [2][1536][512] bf16
    const float* __restrict__ bhh,            // [2][1536]
    unsigned* __restrict__ hb32,              // [2][2][32][512] u32 tagged
    float* __restrict__ out)                  // encoded + hidden
{
  __shared__ __align__(16) unsigned short Wl[48 * 512];  // 48KB, swizzled

  const int bid = blockIdx.x;
  const int d = bid >> 5;
  const int wg = bid & 31;
  const int j0 = wg * JW;
  const int tid = threadIdx.x;
  const int l = tid & 63;
  const int w = tid >> 6;       // wave = b-half

  // stage W_hh slice: rows lr = gate*16 + jj  ->  global row gate*512+j0+jj
  for (int it = 0; it < 24; ++it) {
    int c = it * 128 + tid;      // 16B chunks; 64 per row
    int lr = c >> 6, kc = c & 63;
    int gate = lr >> 4, jj = lr & 15;
    uint4 v = *(const uint4*)(whh +
        (size_t)(d * 1536 + gate * 512 + j0 + jj) * 512 + kc * 8);
    unsigned off = (unsigned)(lr * 1024 + kc * 16); off ^= (lr & 7) << 4;
    *(uint4*)((char*)Wl + off) = v;
  }

  const int jl = l & 15;
  const int jglob = j0 + jl;
  const int b0 = w * 16;
  const int brow = b0 + (l >> 4) * 4;   // first of 4 C-rows (batch) this lane owns
  const float bh_r = bhh[d * 1536 + jglob];
  const float bh_z = bhh[d * 1536 + 512 + jglob];
  const float bh_n = bhh[d * 1536 + 1024 + jglob];

  float hold[4] = {0.f, 0.f, 0.f, 0.f};

  __syncthreads();  // Wl ready (only barrier in the kernel)

  // prefetch gx for t=0
  bf16x4 gr, gz, gn;
  {
    size_t gb = (size_t)d * 1536 * 32;
    gr = *(const bf16x4*)(gx + gb + (size_t)jglob * 32 + brow);
    gz = *(const bf16x4*)(gx + gb + (size_t)(512 + jglob) * 32 + brow);
    gn = *(const bf16x4*)(gx + gb + (size_t)(1024 + jglob) * 32 + brow);
  }

  for (int t = 0; t < SEQL; ++t) {
    f32x4 accr = {0.f, 0.f, 0.f, 0.f};
    f32x4 accz = accr, accn = accr;

    if (t > 0) {
      const unsigned tagv = (unsigned)t;
      const size_t pbase = (size_t)(d * 2 + ((t - 1) & 1)) * 32 * 512;

      // ---- canary poll: one 4B tagged word per lane; producer p = l&31,
      //      row = this wave's own b-half row (written by producer's wave w)
      {
        const unsigned* cp = hb32 + pbase +
            (size_t)(b0 + (l & 15)) * 512 + (size_t)(l & 31) * 16;
        for (;;) {
          unsigned cv = __hip_atomic_load(cp, RLX, AGENT);
          if (__ballot((cv >> 16) == tagv) == ~0ull) break;
          __builtin_amdgcn_s_sleep(1);
        }
      }

      // ---- one-shot bulk read, tag-validated; retries rare (store-order)
      const unsigned long long* hq = (const unsigned long long*)(hb32 + pbase);
      const unsigned long long* hqb =
          hq + (size_t)(b0 + (l & 15)) * 256 + (l >> 4) * 4;
      unsigned long long qv[64];
      for (;;) {
#pragma unroll
        for (int ks = 0; ks < 16; ++ks)
#pragma unroll
          for (int u = 0; u < 4; ++u)
            qv[ks * 4 + u] = __hip_atomic_load(hqb + ks * 16 + u, RLX, AGENT);
        // min over all 128 tagged u32: high16(min) == min tag (tags never > t)
        unsigned mn[64];
#pragma unroll
        for (int i = 0; i < 64; ++i) {
          unsigned lo = (unsigned)qv[i], hi = (unsigned)(qv[i] >> 32);
          mn[i] = lo < hi ? lo : hi;
        }
#pragma unroll
        for (int st = 32; st; st >>= 1)
#pragma unroll
          for (int i = 0; i < st; ++i)
            mn[i] = mn[i] < mn[i + st] ? mn[i] : mn[i + st];
        if (__ballot((mn[0] >> 16) == tagv) == ~0ull) break;
        __builtin_amdgcn_s_sleep(1);
      }

      // repack low halves -> bf16x8 A-frags, then MFMA
#pragma unroll
      for (int ks = 0; ks < 16; ++ks) {
        union { unsigned u[4]; bf16x8 v; } af;
#pragma unroll
        for (int u = 0; u < 4; ++u) {
          unsigned long long qq = qv[ks * 4 + u];
          af.u[u] = __builtin_amdgcn_perm((unsigned)(qq >> 32), (unsigned)qq,
                                          0x05040100u);
        }
        unsigned kb = (unsigned)(ks * 64 + (l >> 4) * 16);
        unsigned r0 = (unsigned)jl, r1 = (unsigned)(16 + jl), r2 = (unsigned)(32 + jl);
        bf16x8 bR = *(const bf16x8*)((char*)Wl + ((r0 * 1024 + kb) ^ ((r0 & 7) << 4)));
        bf16x8 bZ = *(const bf16x8*)((char*)Wl + ((r1 * 1024 + kb) ^ ((r1 & 7) << 4)));
        bf16x8 bN = *(const bf16x8*)((char*)Wl + ((r2 * 1024 + kb) ^ ((r2 & 7) << 4)));
        accr = __builtin_amdgcn_mfma_f32_16x16x32_bf16(af.v, bR, accr, 0, 0, 0);
        accz = __builtin_amdgcn_mfma_f32_16x16x32_bf16(af.v, bZ, accz, 0, 0, 0);
        accn = __builtin_amdgcn_mfma_f32_16x16x32_bf16(af.v, bN, accn, 0, 0, 0);
      }
    }

    unsigned* hnout = hb32 + (size_t)(d * 2 + (t & 1)) * 32 * 512;
    const unsigned tagw = ((unsigned)(t + 1)) << 16;
#pragma unroll
    for (int i = 0; i < 4; ++i) {
      float ghr = accr[i] + bh_r;
      float ghz = accz[i] + bh_z;
      float ghn = accn[i] + bh_n;
      float pr = bf2f(gr[i]) + ghr;
      float pz = bf2f(gz[i]) + ghz;
      float r = 1.f / (1.f + __expf(-pr));
      float z = 1.f / (1.f + __expf(-pz));
      float n = tanhf(bf2f(gn[i]) + r * ghn);
      float h = (1.f - z) * n + z * hold[i];
      hold[i] = h;
      if (t < SEQL - 1)
        __hip_atomic_store(hnout + (size_t)(brow + i) * 512 + jglob,
                           tagw | (unsigned)f2bf(h), RLX, AGENT);
    }
#pragma unroll
    for (int i = 0; i < 4; ++i)
      out[((size_t)(brow + i) * SEQL + t) * 1024 + d * 512 + jglob] = hold[i];
    if (t == SEQL - 1) {
#pragma unroll
      for (int i = 0; i < 4; ++i)
        out[(size_t)BATCH * SEQL * 1024 +
            (size_t)(d * 32 + brow + i) * 512 + jglob] = hold[i];
    }

    if (t < SEQL - 1) {
      // prefetch next gx (independent of h), overlaps peers' publish latency
      size_t gb = ((size_t)(t + 1) * 2 + d) * 1536 * 32;
      gr = *(const bf16x4*)(gx + gb + (size_t)jglob * 32 + brow);
      gz = *(const bf16x4*)(gx + gb + (size_t)(512 + jglob) * 32 + brow);
      gn = *(const bf16x4*)(gx + gb + (size_t)(1024 + jglob) * 32 + brow);
    }
  }
}

extern "C" void kernel_launch(void* const* d_in, const int* in_sizes, int n_in,
                              void* d_out, int out_size, void* d_ws, size_t ws_size,
                              hipStream_t stream) {
  const int* enc = (const int*)d_in[0];
  const float* emb = (const float*)d_in[1];
  const float* wih = (const float*)d_in[2];
  const float* whh = (const float*)d_in[3];
  const float* bih = (const float*)d_in[4];
  const float* bhh = (const float*)d_in[5];
  float* out = (float*)d_out;

  char* ws = (char*)d_ws;
  // layout (16B aligned):
  //   [0, 262144)  hb32 tagged h  2*2*32*512*4
  //   then whh_b 3145728, wih_b 3145728, emb_b 32768000, gx 100663296
  unsigned* hb32 = (unsigned*)ws;
  unsigned short* whh_b = (unsigned short*)(ws + 262144);
  unsigned short* wih_b = (unsigned short*)(ws + 262144 + 3145728);
  unsigned short* emb_b = (unsigned short*)(ws + 262144 + 2 * 3145728);
  unsigned short* gx = (unsigned short*)(ws + 262144 + 2 * 3145728 + 32768000);

  hipMemsetAsync(hb32, 0, 262144, stream);  // clear tags (graph-replayed)
  cvt_f32_bf16<<<768, 256, 0, stream>>>(whh, whh_b, 196608);
  cvt_f32_bf16<<<768, 256, 0, stream>>>(wih, wih_b, 196608);
  cvt_f32_bf16<<<8000, 256, 0, stream>>>(emb, emb_b, 2048000);
  gemm_gx<<<dim3(24, 128), 256, 0, stream>>>(enc, emb_b, wih_b, bih, gx);
  scan_gru<<<64, 128, 0, stream>>>(gx, whh_b, bhh, hb32, out);
}

// Round 8
// 1988.987 us; speedup vs baseline: 2.5317x; 1.5511x over previous
//
#include <hip/hip_runtime.h>
#include <stdint.h>

#define VOCAB 32000
#define EMBD 512
#define HID 512
#define BATCH 32
#define SEQL 512

typedef short bf16x8 __attribute__((ext_vector_type(8)));
typedef short bf16x4 __attribute__((ext_vector_type(4)));
typedef float f32x4 __attribute__((ext_vector_type(4)));

#define AGENT __HIP_MEMORY_SCOPE_AGENT
#define RLX __ATOMIC_RELAXED

static __device__ __forceinline__ float bf2f(short u) {
  union { unsigned u; float f; } c;
  c.u = ((unsigned)(unsigned short)u) << 16;
  return c.f;
}
static __device__ __forceinline__ unsigned short f2bf(float f) {
  union { float f; unsigned u; } c;
  c.f = f;
  unsigned x = c.u;
  unsigned r = (x + 0x7fffu + ((x >> 16) & 1u)) >> 16;
  return (unsigned short)r;
}

// ---------------- f32 -> bf16 convert (8 elems/thread) ----------------
__global__ __launch_bounds__(256) void cvt_f32_bf16(
    const float* __restrict__ src, unsigned short* __restrict__ dst, int n8) {
  int i = blockIdx.x * 256 + threadIdx.x;
  if (i >= n8) return;
  const float4* s = (const float4*)src + (size_t)i * 2;
  float4 a = s[0], b = s[1];
  uint4 p;
  p.x = (unsigned)f2bf(a.x) | ((unsigned)f2bf(a.y) << 16);
  p.y = (unsigned)f2bf(a.z) | ((unsigned)f2bf(a.w) << 16);
  p.z = (unsigned)f2bf(b.x) | ((unsigned)f2bf(b.y) << 16);
  p.w = (unsigned)f2bf(b.z) | ((unsigned)f2bf(b.w) << 16);
  ((uint4*)dst)[i] = p;
}

// ---------------- gx GEMM: gx[s][d][g][b] = x[b,s,:]·W_ih[d,g,:] + b_ih ----
#define GBM 128
#define GBN 128
#define GBK 64

__global__ __launch_bounds__(256) void gemm_gx(
    const int* __restrict__ enc,                 // [B][S]
    const unsigned short* __restrict__ embb,     // [VOCAB][512] bf16
    const unsigned short* __restrict__ wih,      // [3072][512] bf16
    const float* __restrict__ b_ih,              // [3072]
    unsigned short* __restrict__ gx)             // [S][2][1536][32] bf16
{
  __shared__ __align__(16) unsigned short As[GBM * GBK];
  __shared__ __align__(16) unsigned short Bs[GBN * GBK];
  __shared__ int tokl[GBM];

  const int n0 = blockIdx.x * GBN;
  const int m0 = blockIdx.y * GBM;
  const int tid = threadIdx.x;
  if (tid < GBM) {
    int m = m0 + tid;
    tokl[tid] = enc[(m & 31) * SEQL + (m >> 5)];
  }
  __syncthreads();

  const int l = tid & 63, w = tid >> 6;
  const int wr = w >> 1, wc = w & 1;

  f32x4 acc[4][4];
  f32x4 zero = {0.f, 0.f, 0.f, 0.f};
#pragma unroll
  for (int mt = 0; mt < 4; ++mt)
#pragma unroll
    for (int nt = 0; nt < 4; ++nt) acc[mt][nt] = zero;

  for (int kt = 0; kt < 512; kt += GBK) {
#pragma unroll
    for (int it = 0; it < 4; ++it) {  // A stage
      int c = it * 256 + tid;
      int r = c >> 3, kc = c & 7;
      uint4 v = *(const uint4*)(embb + (size_t)tokl[r] * 512 + kt + kc * 8);
      unsigned off = (unsigned)(r * 128 + kc * 16); off ^= (r & 7) << 4;
      *(uint4*)((char*)As + off) = v;
    }
#pragma unroll
    for (int it = 0; it < 4; ++it) {  // B stage
      int c = it * 256 + tid;
      int r = c >> 3, kc = c & 7;
      uint4 v = *(const uint4*)(wih + (size_t)(n0 + r) * 512 + kt + kc * 8);
      unsigned off = (unsigned)(r * 128 + kc * 16); off ^= (r & 7) << 4;
      *(uint4*)((char*)Bs + off) = v;
    }
    __syncthreads();
#pragma unroll
    for (int ks = 0; ks < 2; ++ks) {
      bf16x8 af[4], bfr[4];
#pragma unroll
      for (int mt = 0; mt < 4; ++mt) {
        int r = wr * 64 + mt * 16 + (l & 15);
        unsigned off = (unsigned)(r * 128 + ks * 64 + (l >> 4) * 16);
        off ^= (r & 7) << 4;
        af[mt] = *(const bf16x8*)((char*)As + off);
      }
#pragma unroll
      for (int nt = 0; nt < 4; ++nt) {
        int r = wc * 64 + nt * 16 + (l & 15);
        unsigned off = (unsigned)(r * 128 + ks * 64 + (l >> 4) * 16);
        off ^= (r & 7) << 4;
        bfr[nt] = *(const bf16x8*)((char*)Bs + off);
      }
#pragma unroll
      for (int mt = 0; mt < 4; ++mt)
#pragma unroll
        for (int nt = 0; nt < 4; ++nt)
          acc[mt][nt] = __builtin_amdgcn_mfma_f32_16x16x32_bf16(
              af[mt], bfr[nt], acc[mt][nt], 0, 0, 0);
    }
    __syncthreads();
  }

#pragma unroll
  for (int nt = 0; nt < 4; ++nt) {
    int n = n0 + wc * 64 + nt * 16 + (l & 15);
    int d = n >= 1536 ? 1 : 0;
    int g = n - d * 1536;
    float bias = b_ih[n];
#pragma unroll
    for (int mt = 0; mt < 4; ++mt) {
      int mbase = m0 + wr * 64 + mt * 16 + (l >> 4) * 4;
      int s = mbase >> 5;
      int b = mbase & 31;
      unsigned v0 = (unsigned)f2bf(acc[mt][nt][0] + bias) |
                    ((unsigned)f2bf(acc[mt][nt][1] + bias) << 16);
      unsigned v1 = (unsigned)f2bf(acc[mt][nt][2] + bias) |
                    ((unsigned)f2bf(acc[mt][nt][3] + bias) << 16);
      size_t off = ((size_t)(s * 2 + d) * 1536 + g) * 32 + b;
      uint2 pv; pv.x = v0; pv.y = v1;
      *(uint2*)(gx + off) = pv;
    }
  }
}

// ---------------- persistent GRU scan: R2 protocol, de-overheaded ----------
// 64 WGs = 2 dirs x 32 j-slices (JW=16), 128 thr = 2 waves (b-halves).
// All cross-WG traffic = relaxed sc1 agent atomics (only proven transport).
// Per-WAVE rings (b-halves independent, no in-loop __syncthreads):
//   iter t: [poll 32 per-WG flags >= t] -> bulk-read h_{t-1} (untagged bf16,
//   256B/lane, once) -> MFMA -> gates -> publish h_t (2 packed u32 stores)
//   -> wave-local vmcnt(0) drain -> lane0 flag store F=t+1 -> out stores +
//   gx prefetch (off the drain path).
// Lapping-safe: wait->read->publish order; F_c >= t implies c finished
// reading h_{t-2}, so overwriting parity t&1 is safe (R2 proof).
#define JW 16

__global__ __launch_bounds__(128) void scan_gru(
    const unsigned short* __restrict__ gx,    // [S][2][1536][32]
    const unsigned short* __restrict__ whh,   // [2][1536][512] bf16
    const float* __restrict__ bhh,            // [2][1536]
    unsigned short* __restrict__ hbuf,        // [2][2][32][512] bf16
    unsigned* __restrict__ flags,             // [2][2][32] u32, 64B stride
    float* __restrict__ out)                  // encoded + hidden
{
  __shared__ __align__(16) unsigned short Wl[48 * 512];  // 48KB, swizzled

  const int bid = blockIdx.x;
  const int d = bid >> 5;
  const int wg = bid & 31;
  const int j0 = wg * JW;
  const int tid = threadIdx.x;
  const int l = tid & 63;
  const int w = tid >> 6;       // wave = b-half (independent ring)

  // stage W_hh slice: rows lr = gate*16 + jj  ->  global row gate*512+j0+jj
  for (int it = 0; it < 24; ++it) {
    int c = it * 128 + tid;      // 16B chunks; 64 per row
    int lr = c >> 6, kc = c & 63;
    int gate = lr >> 4, jj = lr & 15;
    uint4 v = *(const uint4*)(whh +
        (size_t)(d * 1536 + gate * 512 + j0 + jj) * 512 + kc * 8);
    unsigned off = (unsigned)(lr * 1024 + kc * 16); off ^= (lr & 7) << 4;
    *(uint4*)((char*)Wl + off) = v;
  }

  const int jl = l & 15;
  const int jglob = j0 + jl;
  const int b0 = w * 16;
  const int brow = b0 + (l >> 4) * 4;   // first of 4 C-rows (batch) this lane owns
  const float bh_r = bhh[d * 1536 + jglob];
  const float bh_z = bhh[d * 1536 + 512 + jglob];
  const float bh_n = bhh[d * 1536 + 1024 + jglob];

  // per-wave ring flags: [d][w][wg] at 64B stride
  unsigned* myflag = flags + ((size_t)(d * 2 + w) * 32 + wg) * 16;
  const unsigned* fbase = flags + (size_t)(d * 2 + w) * 32 * 16;

  float hold[4] = {0.f, 0.f, 0.f, 0.f};

  __syncthreads();  // Wl ready (only barrier in the kernel)

  // prefetch gx for t=0
  bf16x4 gr, gz, gn;
  {
    size_t gb = (size_t)d * 1536 * 32;
    gr = *(const bf16x4*)(gx + gb + (size_t)jglob * 32 + brow);
    gz = *(const bf16x4*)(gx + gb + (size_t)(512 + jglob) * 32 + brow);
    gn = *(const bf16x4*)(gx + gb + (size_t)(1024 + jglob) * 32 + brow);
  }

  for (int t = 0; t < SEQL; ++t) {
    f32x4 accr = {0.f, 0.f, 0.f, 0.f};
    f32x4 accz = accr, accn = accr;

    if (t > 0) {
      const unsigned tagv = (unsigned)t;
      // ---- poll 32 per-WG flags (lanes 0..31, one flag each) ----
      for (;;) {
        unsigned fv = tagv;
        if (l < 32)
          fv = __hip_atomic_load(fbase + (size_t)l * 16, RLX, AGENT);
        if (__ballot(fv >= tagv) == ~0ull) break;
        __builtin_amdgcn_s_sleep(1);
      }
      // ---- one-shot bulk read of h_{t-1} (untagged bf16, 256B/lane) ----
      const unsigned long long* hq = (const unsigned long long*)
          (hbuf + (size_t)(d * 2 + ((t - 1) & 1)) * 32 * 512);
      size_t qb = (size_t)(b0 + (l & 15)) * 128 + (l >> 4) * 2;  // u64 units
      union { unsigned long long q[2]; bf16x8 v; } afu[16];
#pragma unroll
      for (int ks = 0; ks < 16; ++ks) {
        afu[ks].q[0] = __hip_atomic_load(hq + qb + ks * 8, RLX, AGENT);
        afu[ks].q[1] = __hip_atomic_load(hq + qb + ks * 8 + 1, RLX, AGENT);
      }
#pragma unroll
      for (int ks = 0; ks < 16; ++ks) {
        unsigned kb = (unsigned)(ks * 64 + (l >> 4) * 16);
        unsigned r0 = (unsigned)jl, r1 = (unsigned)(16 + jl), r2 = (unsigned)(32 + jl);
        bf16x8 bR = *(const bf16x8*)((char*)Wl + ((r0 * 1024 + kb) ^ ((r0 & 7) << 4)));
        bf16x8 bZ = *(const bf16x8*)((char*)Wl + ((r1 * 1024 + kb) ^ ((r1 & 7) << 4)));
        bf16x8 bN = *(const bf16x8*)((char*)Wl + ((r2 * 1024 + kb) ^ ((r2 & 7) << 4)));
        accr = __builtin_amdgcn_mfma_f32_16x16x32_bf16(afu[ks].v, bR, accr, 0, 0, 0);
        accz = __builtin_amdgcn_mfma_f32_16x16x32_bf16(afu[ks].v, bZ, accz, 0, 0, 0);
        accn = __builtin_amdgcn_mfma_f32_16x16x32_bf16(afu[ks].v, bN, accn, 0, 0, 0);
      }
    }

    // gates
#pragma unroll
    for (int i = 0; i < 4; ++i) {
      float ghr = accr[i] + bh_r;
      float ghz = accz[i] + bh_z;
      float ghn = accn[i] + bh_n;
      float pr = bf2f(gr[i]) + ghr;
      float pz = bf2f(gz[i]) + ghz;
      float r = 1.f / (1.f + __expf(-pr));
      float z = 1.f / (1.f + __expf(-pz));
      float n = tanhf(bf2f(gn[i]) + r * ghn);
      hold[i] = (1.f - z) * n + z * hold[i];
    }

    if (t < SEQL - 1) {
      // publish h_t: pack neighbor-lane pairs -> 2 aligned u32 sc1 stores
      unsigned* hn32 = (unsigned*)(hbuf + (size_t)(d * 2 + (t & 1)) * 32 * 512);
      unsigned mybf[4], pare[4];
#pragma unroll
      for (int i = 0; i < 4; ++i) mybf[i] = f2bf(hold[i]);
#pragma unroll
      for (int i = 0; i < 4; ++i) {
        unsigned ot = (unsigned)__shfl_xor((int)mybf[i], 1);
        pare[i] = (jl & 1) ? (ot | (mybf[i] << 16)) : (mybf[i] | (ot << 16));
      }
      int jc2 = (j0 + (jl & ~1)) >> 1;  // u32 column index
      int i0 = (jl & 1) ? 2 : 0;
      __hip_atomic_store(hn32 + (size_t)(brow + i0) * 256 + jc2, pare[i0],
                         RLX, AGENT);
      __hip_atomic_store(hn32 + (size_t)(brow + i0 + 1) * 256 + jc2,
                         pare[i0 + 1], RLX, AGENT);
      // wave-local drain: h stores acked at MALL before flag store issues
      asm volatile("s_waitcnt vmcnt(0)" ::: "memory");
      if (l == 0)
        __hip_atomic_store(myflag, (unsigned)(t + 1), RLX, AGENT);
    }

    // out stores + gx prefetch: off the drain-critical path
#pragma unroll
    for (int i = 0; i < 4; ++i)
      out[((size_t)(brow + i) * SEQL + t) * 1024 + d * 512 + jglob] = hold[i];
    if (t == SEQL - 1) {
#pragma unroll
      for (int i = 0; i < 4; ++i)
        out[(size_t)BATCH * SEQL * 1024 +
            (size_t)(d * 32 + brow + i) * 512 + jglob] = hold[i];
    }

    if (t < SEQL - 1) {
      size_t gb = ((size_t)(t + 1) * 2 + d) * 1536 * 32;
      gr = *(const bf16x4*)(gx + gb + (size_t)jglob * 32 + brow);
      gz = *(const bf16x4*)(gx + gb + (size_t)(512 + jglob) * 32 + brow);
      gn = *(const bf16x4*)(gx + gb + (size_t)(1024 + jglob) * 32 + brow);
    }
  }
}

extern "C" void kernel_launch(void* const* d_in, const int* in_sizes, int n_in,
                              void* d_out, int out_size, void* d_ws, size_t ws_size,
                              hipStream_t stream) {
  const int* enc = (const int*)d_in[0];
  const float* emb = (const float*)d_in[1];
  const float* wih = (const float*)d_in[2];
  const float* whh = (const float*)d_in[3];
  const float* bih = (const float*)d_in[4];
  const float* bhh = (const float*)d_in[5];
  float* out = (float*)d_out;

  char* ws = (char*)d_ws;
  // layout (16B aligned):
  //   [0, 8192)        flags [2][2][32] u32 @64B stride
  //   [8192, 139264)   hbuf  2*2*32*512*2 = 131072
  //   then whh_b 3145728, wih_b 3145728, emb_b 32768000, gx 100663296
  unsigned* flags = (unsigned*)ws;
  unsigned short* hbuf = (unsigned short*)(ws + 8192);
  unsigned short* whh_b = (unsigned short*)(ws + 139264);
  unsigned short* wih_b = (unsigned short*)(ws + 139264 + 3145728);
  unsigned short* emb_b = (unsigned short*)(ws + 139264 + 2 * 3145728);
  unsigned short* gx = (unsigned short*)(ws + 139264 + 2 * 3145728 + 32768000);

  hipMemsetAsync(flags, 0, 8192, stream);
  cvt_f32_bf16<<<768, 256, 0, stream>>>(whh, whh_b, 196608);
  cvt_f32_bf16<<<768, 256, 0, stream>>>(wih, wih_b, 196608);
  cvt_f32_bf16<<<8000, 256, 0, stream>>>(emb, emb_b, 2048000);
  gemm_gx<<<dim3(24, 128), 256, 0, stream>>>(enc, emb_b, wih_b, bih, gx);
  scan_gru<<<64, 128, 0, stream>>>(gx, whh_b, bhh, hbuf, flags, out);
}